// Round 9
// baseline (268.428 us; speedup 1.0000x reference)
//
#include <hip/hip_runtime.h>
#include <math.h>

// B=2, S=2048, D_MODEL=1024, D_KV=64, N_HEADS=16, KV_HEADS=4, G=4
// Pipeline (bf16 MFMA, fp32 accumulate):
//   prep_all: cast hs hi/lo; WqkT hi/lo; WvT/WoT bf16; bias table   (1 launch)
//   proj_qkv: 768 blocks (8 QK + 16 V col-tiles, all 64-wide) x 32 row-tiles
//     48KB LDS pool -> 3 blocks/CU. Vb does NOT alias any proj input (R5/R6 lesson).
//   attn: 256-thr blocks, 64 q-rows, 32-token s-tiles, split-s x2, grid 512,
//     52KB LDS -> 3 blocks/CU (3 independent barrier domains). Online softmax.
//   combine: softmax-weighted merge -> ctx bf16
//   gemm_out: 128x64 tiles, grid 512 -> fp32 out

typedef __bf16 bf16_t;
typedef bf16_t bf16x8 __attribute__((ext_vector_type(8)));
typedef bf16_t bf16x4 __attribute__((ext_vector_type(4)));
typedef float f32x4 __attribute__((ext_vector_type(4)));

#define MFMA16(a, b, c) __builtin_amdgcn_mfma_f32_16x16x32_bf16(a, b, c, 0, 0, 0)

typedef __attribute__((address_space(1))) void gvoid;
typedef __attribute__((address_space(3))) void svoid;
__device__ __forceinline__ void gld16(const void* g, void* l) {
    __builtin_amdgcn_global_load_lds((gvoid*)g, (svoid*)l, 16, 0, 0);
}

// ---------------- prep_all: fused block-range dispatch ----------------
__global__ __launch_bounds__(256) void prep_all(const float* __restrict__ hs,
                                                const float* __restrict__ Wq,
                                                const float* __restrict__ Wk,
                                                const float* __restrict__ Wv,
                                                const float* __restrict__ Wo,
                                                const float* __restrict__ rel_bias,
                                                bf16_t* __restrict__ hs_hi,
                                                bf16_t* __restrict__ hs_lo,
                                                bf16_t* __restrict__ Thi,
                                                bf16_t* __restrict__ Tlo,
                                                bf16_t* __restrict__ WvT,
                                                bf16_t* __restrict__ WoT,
                                                float* __restrict__ btab) {
    __shared__ float sm[2048];
    const int r = blockIdx.x, t = threadIdx.x;
    if (r < 4096) {
        size_t idx = ((size_t)r * 256 + t) * 4;
        float4 v = *(const float4*)(hs + idx);
        bf16x4 h, l;
        h[0] = (bf16_t)v.x; l[0] = (bf16_t)(v.x - (float)h[0]);
        h[1] = (bf16_t)v.y; l[1] = (bf16_t)(v.y - (float)h[1]);
        h[2] = (bf16_t)v.z; l[2] = (bf16_t)(v.z - (float)h[2]);
        h[3] = (bf16_t)v.w; l[3] = (bf16_t)(v.w - (float)h[3]);
        *(bf16x4*)(hs_hi + idx) = h;
        *(bf16x4*)(hs_lo + idx) = l;
    } else if (r < 5120) {
        int k = r - 4096;
        float* rq = sm;
        float* rk = sm + 1024;
#pragma unroll
        for (int j = 0; j < 4; ++j) {
            rq[t + j * 256] = Wq[(size_t)k * 1024 + t + j * 256];
            rk[t + j * 256] = Wk[(size_t)k * 1024 + t + j * 256];
        }
        __syncthreads();
        int h = t >> 6, j2 = t & 63;
        float sq = 0.f, sk = 0.f;
#pragma unroll
        for (int g = 0; g < 4; ++g) {
            sq += rq[(g * 4 + h) * 64 + j2];
            sk += rk[(g * 4 + h) * 64 + j2];
        }
        sk *= 0.25f;
        bf16_t qh = (bf16_t)sq;
        Thi[(size_t)t * 1024 + k] = qh;
        Tlo[(size_t)t * 1024 + k] = (bf16_t)(sq - (float)qh);
        bf16_t kh = (bf16_t)sk;
        Thi[(size_t)(256 + t) * 1024 + k] = kh;
        Tlo[(size_t)(256 + t) * 1024 + k] = (bf16_t)(sk - (float)kh);
    } else if (r < 7168) {
        const float* src = (r < 6144) ? Wv : Wo;
        bf16_t* dst = (r < 6144) ? WvT : WoT;
        int rr = (r < 6144) ? r - 5120 : r - 6144;
        int bx = (rr & 31) * 32, by = (rr >> 5) * 32;
        int tx = t & 31, ty = t >> 5;
        float(*tile)[33] = (float(*)[33])sm;
#pragma unroll
        for (int i = 0; i < 32; i += 8)
            tile[ty + i][tx] = src[(size_t)(by + ty + i) * 1024 + bx + tx];
        __syncthreads();
#pragma unroll
        for (int i = 0; i < 32; i += 8)
            dst[(size_t)(bx + ty + i) * 1024 + by + tx] = (bf16_t)tile[tx][ty + i];
    } else {
        int idx = (r - 7168) * 256 + t;
        if (idx >= 4095) return;
        int delta = idx - 2047;
        int bucket = (delta > 0) ? 16 : 0;
        int arp = delta < 0 ? -delta : delta;
        int rb;
        if (arp < 8) {
            rb = arp;
        } else {
            float tt = (logf((float)arp * 0.125f) / 2.772588722239781f) * 8.0f;
            int ri = 8 + (int)tt;
            rb = ri < 15 ? ri : 15;
        }
        bucket += rb;
#pragma unroll
        for (int h = 0; h < 4; ++h) {
            float s = 0.25f * (rel_bias[bucket * 16 + h] + rel_bias[bucket * 16 + h + 4] +
                               rel_bias[bucket * 16 + h + 8] + rel_bias[bucket * 16 + h + 12]);
            btab[h * 4608 + idx] = s;
        }
    }
}

// ---------------- fused projection GEMM, 768 blocks (3/CU) ----------------
// bx<8:  QK col-tile 64-wide (hi/lo, 3 MFMAs), n0 = bx*64
// bx>=8: V col-tile 64-wide (plain),            n0 = (bx-8)*64
// 48KB pool: [0,8K) elems A-hi dbuf | [8K,16K) A-lo dbuf (QK only) |
//            [16K,20K) B-hi dbuf | [20K,24K) B-lo dbuf (QK only)
__global__ __launch_bounds__(256, 1) void proj_qkv(const bf16_t* __restrict__ Ah,
                                                   const bf16_t* __restrict__ Al,
                                                   const bf16_t* __restrict__ Bh,
                                                   const bf16_t* __restrict__ Bl,
                                                   const bf16_t* __restrict__ WvT,
                                                   bf16_t* __restrict__ Qhi,
                                                   bf16_t* __restrict__ Qlo,
                                                   bf16_t* __restrict__ Kbh,
                                                   bf16_t* __restrict__ Kbl,
                                                   bf16_t* __restrict__ Vb) {
    __shared__ bf16_t pool[24576];  // 48KB
    const int K = 1024, nk = 32;
    const int t = threadIdx.x;
    const int w = t >> 6, lane = t & 63;
    const int lr = lane & 15, q = lane >> 4;
    const int bx = blockIdx.x;
    const bool qk = bx < 8;
    const int m0 = blockIdx.y * 128;
    const int n0 = qk ? bx * 64 : (bx - 8) * 64;
    const int mw = (w & 1) * 64, nw = (w >> 1) * 32;
    f32x4 acc[4][2] = {};

    // A staging: 128-row tile, slot = chunk*128 + row
    const int rA = t & 127, cA0 = t >> 7, cA1 = 2 + (t >> 7);
    const size_t oA0 = (size_t)(m0 + rA) * K + cA0 * 8;
    const size_t oA1 = (size_t)(m0 + rA) * K + cA1 * 8;
    // B staging (both): 64-row tile, slot = chunk*64 + row
    const int rB = t & 63, cB = t >> 6;
    const size_t oB = (size_t)(n0 + rB) * K + cB * 8;
    const bf16_t* Bhi = qk ? Bh : WvT;

    auto stage = [&](int bf, int k0) {
        gld16(Ah + oA0 + k0, &pool[bf * 4096 + t * 8]);
        gld16(Ah + oA1 + k0, &pool[bf * 4096 + (256 + t) * 8]);
        gld16(Bhi + oB + k0, &pool[16384 + bf * 2048 + t * 8]);
        if (qk) {
            gld16(Al + oA0 + k0, &pool[8192 + bf * 4096 + t * 8]);
            gld16(Al + oA1 + k0, &pool[8192 + bf * 4096 + (256 + t) * 8]);
            gld16(Bl + oB + k0, &pool[20480 + bf * 2048 + t * 8]);
        }
    };

    stage(0, 0);
    __syncthreads();
    for (int it = 0; it < nk; ++it) {
        const int cur = it & 1;
        if (it + 1 < nk) stage(cur ^ 1, (it + 1) * 32);
        if (qk) {
            bf16x8 ah[4], al[4], bh[2], bl[2];
#pragma unroll
            for (int i = 0; i < 4; ++i) {
                int sa = (q * 128 + mw + i * 16 + lr) * 8;
                ah[i] = *(const bf16x8*)&pool[cur * 4096 + sa];
                al[i] = *(const bf16x8*)&pool[8192 + cur * 4096 + sa];
            }
#pragma unroll
            for (int j = 0; j < 2; ++j) {
                int sb = (q * 64 + nw + j * 16 + lr) * 8;
                bh[j] = *(const bf16x8*)&pool[16384 + cur * 2048 + sb];
                bl[j] = *(const bf16x8*)&pool[20480 + cur * 2048 + sb];
            }
#pragma unroll
            for (int i = 0; i < 4; ++i)
#pragma unroll
                for (int j = 0; j < 2; ++j) {
                    acc[i][j] = MFMA16(ah[i], bh[j], acc[i][j]);
                    acc[i][j] = MFMA16(ah[i], bl[j], acc[i][j]);
                    acc[i][j] = MFMA16(al[i], bh[j], acc[i][j]);
                }
        } else {
            bf16x8 af[4], bfv[2];
#pragma unroll
            for (int i = 0; i < 4; ++i)
                af[i] = *(const bf16x8*)&pool[cur * 4096 + (q * 128 + mw + i * 16 + lr) * 8];
#pragma unroll
            for (int j = 0; j < 2; ++j)
                bfv[j] = *(const bf16x8*)&pool[16384 + cur * 2048 + (q * 64 + nw + j * 16 + lr) * 8];
#pragma unroll
            for (int i = 0; i < 4; ++i)
#pragma unroll
                for (int j = 0; j < 2; ++j) acc[i][j] = MFMA16(af[i], bfv[j], acc[i][j]);
        }
        __syncthreads();
    }

#pragma unroll
    for (int i = 0; i < 4; ++i) {
        int row = m0 + mw + i * 16 + q * 4;  // token base
#pragma unroll
        for (int j = 0; j < 2; ++j) {
            int col = n0 + nw + j * 16 + lr;
#pragma unroll
            for (int reg = 0; reg < 4; ++reg) {
                float x = acc[i][j][reg];
                int token = row + reg;
                if (qk) {
                    bf16_t hi = (bf16_t)x;
                    bf16_t lo = (bf16_t)(x - (float)hi);
                    if (col < 256) {
                        size_t o = (size_t)token * 256 + col;
                        Qhi[o] = hi;
                        Qlo[o] = lo;
                    } else {
                        // K blocked: per-(b,h,32-tok tile) 2048 elems,
                        // slot = (d>>3)*32 + (s&31), inner d&7
                        int hc = col - 256;
                        int h = hc >> 6, d = hc & 63;
                        int b = token >> 11, s = token & 2047;
                        size_t o = ((size_t)((b * 4 + h) * 64 + (s >> 5))) * 2048 +
                                   (size_t)((d >> 3) * 32 + (s & 31)) * 8 + (d & 7);
                        Kbh[o] = hi;
                        Kbl[o] = lo;
                    }
                } else {
                    // V blocked: per-(b,h,32-tok tile) 8192 elems,
                    // slot = ((s>>3)&3)*256 + g*64 + d, inner s&7
                    int vg = col;
                    int h = (vg >> 6) & 3, g = vg >> 8, d = vg & 63;
                    int b = token >> 11, s = token & 2047;
                    size_t o = ((size_t)((b * 4 + h) * 64 + (s >> 5))) * 8192 +
                               (size_t)(((s >> 3) & 3) * 256 + g * 64 + d) * 8 + (s & 7);
                    Vb[o] = (bf16_t)x;
                }
            }
        }
    }
}

// ---------------- output GEMM: 128x64 tiles, grid 512 ----------------
__global__ __launch_bounds__(256, 1) void gemm_out(const bf16_t* __restrict__ A,
                                                   const bf16_t* __restrict__ BT,
                                                   float* __restrict__ C,
                                                   int M, int N, int K) {
    __shared__ bf16_t pool[12288];  // 24KB
    const int t = threadIdx.x;
    const int w = t >> 6, lane = t & 63;
    const int lr = lane & 15, q = lane >> 4;
    const int m0 = blockIdx.y * 128, n0 = blockIdx.x * 64;
    const int mw = (w & 1) * 64, nw = (w >> 1) * 32;
    f32x4 acc[4][2] = {};
    const int nk = K >> 5;

    const int rA = t & 127, cA0 = t >> 7, cA1 = 2 + (t >> 7);
    const bf16_t* gA0 = A + (size_t)(m0 + rA) * K + cA0 * 8;
    const bf16_t* gA1 = A + (size_t)(m0 + rA) * K + cA1 * 8;
    const bf16_t* gB = BT + (size_t)(n0 + (t & 63)) * K + (t >> 6) * 8;

    auto stage = [&](int bf, int k0) {
        gld16(gA0 + k0, &pool[bf * 4096 + t * 8]);
        gld16(gA1 + k0, &pool[bf * 4096 + (256 + t) * 8]);
        gld16(gB + k0, &pool[8192 + bf * 2048 + t * 8]);
    };

    stage(0, 0);
    __syncthreads();
    for (int it = 0; it < nk; ++it) {
        const int cur = it & 1;
        if (it + 1 < nk) stage(cur ^ 1, (it + 1) * 32);
        bf16x8 af[4], bfv[2];
#pragma unroll
        for (int i = 0; i < 4; ++i)
            af[i] = *(const bf16x8*)&pool[cur * 4096 + (q * 128 + mw + i * 16 + lr) * 8];
#pragma unroll
        for (int j = 0; j < 2; ++j)
            bfv[j] = *(const bf16x8*)&pool[8192 + cur * 2048 + (q * 64 + nw + j * 16 + lr) * 8];
#pragma unroll
        for (int i = 0; i < 4; ++i)
#pragma unroll
            for (int j = 0; j < 2; ++j) acc[i][j] = MFMA16(af[i], bfv[j], acc[i][j]);
        __syncthreads();
    }

#pragma unroll
    for (int i = 0; i < 4; ++i) {
        int row = m0 + mw + i * 16 + q * 4;
#pragma unroll
        for (int j = 0; j < 2; ++j) {
            int col = n0 + nw + j * 16 + lr;
#pragma unroll
            for (int reg = 0; reg < 4; ++reg)
                C[(size_t)(row + reg) * N + col] = acc[i][j][reg];
        }
    }
}

// ---------------- flash attention: 256 threads, 32-token tiles, 3 blocks/CU ----------
// grid 512 = b(2) x h(4) x qtile(32 of 64 rows) x shalf(2); 4 waves x 16 q-rows.
// LDS 52KB. Online softmax (verified loop, ct<2 / PV K=32).
__global__ __launch_bounds__(256, 1) void attn_mfma(const bf16_t* __restrict__ Qhi,
                                                    const bf16_t* __restrict__ Qlo,
                                                    const bf16_t* __restrict__ Kbh,
                                                    const bf16_t* __restrict__ Kbl,
                                                    const bf16_t* __restrict__ Vb,
                                                    const float* __restrict__ btab,
                                                    bf16_t* __restrict__ part0,
                                                    bf16_t* __restrict__ part1,
                                                    float* __restrict__ Sml) {
    __shared__ bf16_t Kh[2][2048], Kl[2][2048], Vsm[2][8192], Ps[2048];
    const int t = threadIdx.x, w = t >> 6, lane = t & 63;
    const int lr = lane & 15, q = lane >> 4;
    const int blk = blockIdx.x;
    const int half = blk & 1, qt = (blk >> 1) & 31, h = (blk >> 6) & 3, b = blk >> 8;
    const int n0 = qt * 64;
    const int rowbase = n0 + w * 16;

    const size_t qrow = (size_t)(b * 2048 + rowbase + lr) * 256 + h * 64;
    bf16x8 aqh[2], aql[2];
#pragma unroll
    for (int kb = 0; kb < 2; ++kb) {
        aqh[kb] = *(const bf16x8*)(Qhi + qrow + kb * 32 + q * 8);
        aql[kb] = *(const bf16x8*)(Qlo + qrow + kb * 32 + q * 8);
    }

    const size_t tb = (size_t)((b * 4 + h) * 64 + half * 32);
    const bf16_t* gK = Kbh + tb * 2048;
    const bf16_t* gL = Kbl + tb * 2048;
    const bf16_t* gV = Vb + tb * 8192;
    const float* btabh = btab + h * 4608 + 2047;

    auto stage = [&](int bf, int it) {
        gld16(gK + (size_t)it * 2048 + t * 8, &Kh[bf][t * 8]);
        gld16(gL + (size_t)it * 2048 + t * 8, &Kl[bf][t * 8]);
        const bf16_t* v0 = gV + (size_t)it * 8192;
#pragma unroll
        for (int j = 0; j < 4; ++j)
            gld16(v0 + (j * 256 + t) * 8, &Vsm[bf][(j * 256 + t) * 8]);
    };

    float m_r[4], l_r[4];
#pragma unroll
    for (int reg = 0; reg < 4; ++reg) { m_r[reg] = -INFINITY; l_r[reg] = 0.f; }
    f32x4 O[16] = {};

    stage(0, 0);
    __syncthreads();
    for (int it = 0; it < 32; ++it) {
        const int cur = it & 1;
        if (it + 1 < 32) stage(cur ^ 1, it + 1);
        const int s0g = half * 1024 + it * 32;

        // scores: 16 rows x 32 cols per wave (hi/lo split)
        f32x4 sc[2];
#pragma unroll
        for (int ct = 0; ct < 2; ++ct) {
            f32x4 z = {0.f, 0.f, 0.f, 0.f};
#pragma unroll
            for (int kb = 0; kb < 2; ++kb) {
                int sb = ((kb * 4 + q) * 32 + ct * 16 + lr) * 8;
                bf16x8 bh = *(const bf16x8*)&Kh[cur][sb];
                bf16x8 bl = *(const bf16x8*)&Kl[cur][sb];
                z = MFMA16(aqh[kb], bh, z);
                z = MFMA16(aqh[kb], bl, z);
                z = MFMA16(aql[kb], bh, z);
            }
            sc[ct] = z;
        }
        const int dbase = (s0g + lr) - (rowbase + q * 4);
#pragma unroll
        for (int ct = 0; ct < 2; ++ct)
#pragma unroll
            for (int reg = 0; reg < 4; ++reg)
                sc[ct][reg] += btabh[dbase + ct * 16 - reg];

        // online softmax (rows wave-local; 16-lane col groups)
        float rm[4];
#pragma unroll
        for (int reg = 0; reg < 4; ++reg) rm[reg] = fmaxf(sc[0][reg], sc[1][reg]);
#pragma unroll
        for (int off = 1; off < 16; off <<= 1)
#pragma unroll
            for (int reg = 0; reg < 4; ++reg)
                rm[reg] = fmaxf(rm[reg], __shfl_xor(rm[reg], off, 64));

        float alpha[4], rs[4];
#pragma unroll
        for (int reg = 0; reg < 4; ++reg) {
            float mo = m_r[reg];
            float mn = fmaxf(mo, rm[reg]);
            alpha[reg] = __expf(mo - mn);
            m_r[reg] = mn;
            rs[reg] = 0.f;
        }
#pragma unroll
        for (int ct = 0; ct < 2; ++ct) {
#pragma unroll
            for (int reg = 0; reg < 4; ++reg) {
                float p = __expf(sc[ct][reg] - m_r[reg]);
                rs[reg] += p;
                int col = ct * 16 + lr;
                Ps[((w * 64 + (col >> 3) * 16) + q * 4 + reg) * 8 + (col & 7)] = (bf16_t)p;
            }
        }
#pragma unroll
        for (int off = 1; off < 16; off <<= 1)
#pragma unroll
            for (int reg = 0; reg < 4; ++reg) rs[reg] += __shfl_xor(rs[reg], off, 64);
#pragma unroll
        for (int reg = 0; reg < 4; ++reg) l_r[reg] = l_r[reg] * alpha[reg] + rs[reg];

        // P A-fragment (wave-private LDS region; K=32 -> single chunk q)
        bf16x8 pa = *(const bf16x8*)&Ps[(w * 64 + q * 16 + lr) * 8];

        // O = alpha*O + P @ V
#pragma unroll
        for (int nt = 0; nt < 16; ++nt) {
            f32x4 o = O[nt];
#pragma unroll
            for (int reg = 0; reg < 4; ++reg) o[reg] *= alpha[reg];
            bf16x8 v = *(const bf16x8*)&Vsm[cur][(q * 256 + nt * 16 + lr) * 8];
            o = MFMA16(pa, v, o);
            O[nt] = o;
        }
        __syncthreads();
    }

    // epilogue: normalized partial O + per-row m+log(l)
    bf16_t* P = half ? part1 : part0;
    float inv[4];
#pragma unroll
    for (int reg = 0; reg < 4; ++reg) inv[reg] = 1.f / l_r[reg];
    const size_t tokbase = (size_t)(b * 2048 + rowbase + q * 4);
#pragma unroll
    for (int nt = 0; nt < 16; ++nt) {
        int v = nt * 16 + lr;
        int vg = ((v >> 6) * 4 + h) * 64 + (v & 63);
#pragma unroll
        for (int reg = 0; reg < 4; ++reg)
            P[(tokbase + reg) * 1024 + vg] = (bf16_t)(O[nt][reg] * inv[reg]);
    }
    if (lr == 0) {
#pragma unroll
        for (int reg = 0; reg < 4; ++reg)
            Sml[half * 16384 + (tokbase + reg) * 4 + h] = m_r[reg] + logf(l_r[reg]);
    }
}

// ---------------- combine the two s-halves (in-place into part0) ----------------
__global__ __launch_bounds__(256) void combine_halves(bf16_t* __restrict__ p0,
                                                      const bf16_t* __restrict__ p1,
                                                      const float* __restrict__ Sml) {
    size_t flat = ((size_t)blockIdx.x * 256 + threadIdx.x) * 8;
    int tok = (int)(flat >> 10), c = (int)(flat & 1023), h = (c >> 6) & 3;
    float s0 = Sml[tok * 4 + h], s1 = Sml[16384 + tok * 4 + h];
    float M = fmaxf(s0, s1);
    float e0 = __expf(s0 - M), e1 = __expf(s1 - M);
    float r = 1.f / (e0 + e1);
    float w0 = e0 * r, w1 = e1 * r;
    bf16x8 a = *(bf16x8*)(p0 + flat);
    bf16x8 bb = *(const bf16x8*)(p1 + flat);
    bf16x8 o;
#pragma unroll
    for (int i = 0; i < 8; ++i) o[i] = (bf16_t)(w0 * (float)a[i] + w1 * (float)bb[i]);
    *(bf16x8*)(p0 + flat) = o;
}

extern "C" void kernel_launch(void* const* d_in, const int* in_sizes, int n_in,
                              void* d_out, int out_size, void* d_ws, size_t ws_size,
                              hipStream_t stream) {
    const float* hs = (const float*)d_in[0];
    const float* Wq = (const float*)d_in[1];
    const float* Wk = (const float*)d_in[2];
    const float* Wv = (const float*)d_in[3];
    const float* Wo = (const float*)d_in[4];
    const float* rb = (const float*)d_in[5];
    float* out = (float*)d_out;

    const size_t MB = 1 << 20;
    const size_t KB = 1 << 10;
    char* ws = (char*)d_ws;
    // Map (peak 38.25 MB). Vb does NOT alias any proj input (R5/R6 lesson).
    bf16_t* hs_hi = (bf16_t*)(ws);                    // dead after proj -> part0/ctx
    bf16_t* hs_lo = (bf16_t*)(ws + 8 * MB);           // dead after proj -> part1
    bf16_t* WqkThi = (bf16_t*)(ws + 16 * MB);
    bf16_t* WqkTlo = (bf16_t*)(ws + 17 * MB);
    bf16_t* WvT = (bf16_t*)(ws + 18 * MB);
    bf16_t* WoT = (bf16_t*)(ws + 20 * MB);
    float* btab = (float*)(ws + 22 * MB);
    float* Sml = (float*)(ws + 22 * MB + 128 * KB);
    bf16_t* Qhi = (bf16_t*)(ws + 22 * MB + 256 * KB);
    bf16_t* Qlo = Qhi + (size_t)4096 * 256;
    bf16_t* Kbh = Qlo + (size_t)4096 * 256;
    bf16_t* Kbl = Kbh + (size_t)4096 * 256;
    bf16_t* Vb = Kbl + (size_t)4096 * 256;  // own 8 MB region
    bf16_t* part0 = hs_hi;
    bf16_t* part1 = hs_lo;

    prep_all<<<7184, 256, 0, stream>>>(hs, Wq, Wk, Wv, Wo, rb, hs_hi, hs_lo, WqkThi,
                                       WqkTlo, WvT, WoT, btab);
    proj_qkv<<<dim3(24, 32), 256, 0, stream>>>(hs_hi, hs_lo, WqkThi, WqkTlo, WvT, Qhi,
                                               Qlo, Kbh, Kbl, Vb);
    attn_mfma<<<512, 256, 0, stream>>>(Qhi, Qlo, Kbh, Kbl, Vb, btab, part0, part1, Sml);
    combine_halves<<<2048, 256, 0, stream>>>(part0, part1, Sml);
    gemm_out<<<dim3(16, 32), 256, 0, stream>>>(part0, WoT, out, 4096, 1024, 1024);
}